// Round 1
// baseline (3251.612 us; speedup 1.0000x reference)
//
#include <hip/hip_runtime.h>

#define D 128
#define BN_EPS 1e-5f

// ---------------- edge scatter: aggr[dst] += relu(x[src] + edge_attr[e]) ----
// one 32-lane group per edge; each lane handles a float4 (32*16B = 512B row)
__global__ __launch_bounds__(256) void k_edge(
    const float* __restrict__ x, const int* __restrict__ ei,
    const float* __restrict__ ea, float* __restrict__ aggr, int E)
{
    int g = (blockIdx.x * 256 + threadIdx.x) >> 5;
    int lane = threadIdx.x & 31;
    if (g >= E) return;
    int src = ei[g];
    int dst = ei[E + g];
    float4 xv = *((const float4*)(x + (size_t)src * D) + lane);
    float4 ev = *((const float4*)(ea + (size_t)g * D) + lane);
    float4 m;
    m.x = fmaxf(xv.x + ev.x, 0.f);
    m.y = fmaxf(xv.y + ev.y, 0.f);
    m.z = fmaxf(xv.z + ev.z, 0.f);
    m.w = fmaxf(xv.w + ev.w, 0.f);
    float* dp = aggr + (size_t)dst * D + lane * 4;
    atomicAdd(dp + 0, m.x);
    atomicAdd(dp + 1, m.y);
    atomicAdd(dp + 2, m.z);
    atomicAdd(dp + 3, m.w);
}

// ---------------- GEMM1: h1 = relu((x+aggr) @ W1 + b1); accumulate BN stats --
// W1 staged in LDS (64KB); 4 waves/block, one row per wave per iteration;
// each lane owns 2 output columns.
__global__ __launch_bounds__(256) void k_gemm1(
    const float* __restrict__ x, const float* __restrict__ aggr,
    const float* __restrict__ W1, const float* __restrict__ b1,
    float* __restrict__ h1, float* __restrict__ gsum, float* __restrict__ gsq,
    int N)
{
    __shared__ float wS[D * D];
    __shared__ float rS[4][D];
    int tid = threadIdx.x;
    for (int i = tid * 4; i < D * D; i += 256 * 4)
        *(float4*)&wS[i] = *(const float4*)&W1[i];
    __syncthreads();

    int wv = tid >> 6, lane = tid & 63;
    int c0 = 2 * lane;
    float bb0 = b1[c0], bb1 = b1[c0 + 1];
    float s0 = 0.f, s1 = 0.f, q0 = 0.f, q1 = 0.f;

    for (int row = blockIdx.x * 4 + wv; row < N; row += gridDim.x * 4) {
        size_t base = (size_t)row * D;
        float2 xv = *(const float2*)&x[base + c0];
        float2 av = *(const float2*)&aggr[base + c0];
        rS[wv][c0] = xv.x + av.x;
        rS[wv][c0 + 1] = xv.y + av.y;
        // wave-synchronous LDS (same wave wrote rS[wv]); DS ops are in-order
        float a0 = bb0, a1 = bb1;
        #pragma unroll
        for (int k = 0; k < D; k += 4) {
            float4 a = *(const float4*)&rS[wv][k];
            float2 w;
            w = *(const float2*)&wS[(k + 0) * D + c0]; a0 = fmaf(a.x, w.x, a0); a1 = fmaf(a.x, w.y, a1);
            w = *(const float2*)&wS[(k + 1) * D + c0]; a0 = fmaf(a.y, w.x, a0); a1 = fmaf(a.y, w.y, a1);
            w = *(const float2*)&wS[(k + 2) * D + c0]; a0 = fmaf(a.z, w.x, a0); a1 = fmaf(a.z, w.y, a1);
            w = *(const float2*)&wS[(k + 3) * D + c0]; a0 = fmaf(a.w, w.x, a0); a1 = fmaf(a.w, w.y, a1);
        }
        a0 = fmaxf(a0, 0.f);
        a1 = fmaxf(a1, 0.f);
        *(float2*)&h1[base + c0] = make_float2(a0, a1);
        s0 += a0; s1 += a1; q0 += a0 * a0; q1 += a1 * a1;
    }
    atomicAdd(&gsum[c0], s0);
    atomicAdd(&gsum[c0 + 1], s1);
    atomicAdd(&gsq[c0], q0);
    atomicAdd(&gsq[c0 + 1], q1);
}

// ---------------- fold BN into W2/b2:  W2' = diag(rstd*gamma) @ W2,
// b2' = (beta - mean*rstd*gamma) @ W2 + b2 -----------------------------------
__global__ __launch_bounds__(128) void k_fold(
    const float* __restrict__ gsum, const float* __restrict__ gsq,
    const float* __restrict__ gamma, const float* __restrict__ beta,
    const float* __restrict__ W2, const float* __restrict__ b2,
    float* __restrict__ W2p, float* __restrict__ b2p, int N)
{
    __shared__ float sS[D], tS[D];
    int j = threadIdx.x;
    float invN = 1.0f / (float)N;
    float mean = gsum[j] * invN;
    float var = gsq[j] * invN - mean * mean;
    float rstd = rsqrtf(var + BN_EPS);
    float s = rstd * gamma[j];
    sS[j] = s;
    tS[j] = beta[j] - mean * s;
    __syncthreads();
    float acc = b2[j];
    #pragma unroll 4
    for (int k = 0; k < D; ++k) {
        float w = W2[k * D + j];
        W2p[k * D + j] = sS[k] * w;
        acc = fmaf(tS[k], w, acc);
    }
    b2p[j] = acc;
}

// ---------------- GEMM2: out = h1 @ W2' + b2'  (in-place over d_out) --------
__global__ __launch_bounds__(256) void k_gemm2(
    const float* __restrict__ hin, const float* __restrict__ W2p,
    const float* __restrict__ b2p, float* __restrict__ out, int N)
{
    __shared__ float wS[D * D];
    __shared__ float rS[4][D];
    int tid = threadIdx.x;
    for (int i = tid * 4; i < D * D; i += 256 * 4)
        *(float4*)&wS[i] = *(const float4*)&W2p[i];
    __syncthreads();

    int wv = tid >> 6, lane = tid & 63;
    int c0 = 2 * lane;
    float bb0 = b2p[c0], bb1 = b2p[c0 + 1];

    for (int row = blockIdx.x * 4 + wv; row < N; row += gridDim.x * 4) {
        size_t base = (size_t)row * D;
        float2 hv = *(const float2*)&hin[base + c0];
        rS[wv][c0] = hv.x;
        rS[wv][c0 + 1] = hv.y;
        float a0 = bb0, a1 = bb1;
        #pragma unroll
        for (int k = 0; k < D; k += 4) {
            float4 a = *(const float4*)&rS[wv][k];
            float2 w;
            w = *(const float2*)&wS[(k + 0) * D + c0]; a0 = fmaf(a.x, w.x, a0); a1 = fmaf(a.x, w.y, a1);
            w = *(const float2*)&wS[(k + 1) * D + c0]; a0 = fmaf(a.y, w.x, a0); a1 = fmaf(a.y, w.y, a1);
            w = *(const float2*)&wS[(k + 2) * D + c0]; a0 = fmaf(a.z, w.x, a0); a1 = fmaf(a.z, w.y, a1);
            w = *(const float2*)&wS[(k + 3) * D + c0]; a0 = fmaf(a.w, w.x, a0); a1 = fmaf(a.w, w.y, a1);
        }
        *(float2*)&out[base + c0] = make_float2(a0, a1);
    }
}

extern "C" void kernel_launch(void* const* d_in, const int* in_sizes, int n_in,
                              void* d_out, int out_size, void* d_ws, size_t ws_size,
                              hipStream_t stream) {
    const float* x     = (const float*)d_in[0];
    const int*   ei    = (const int*)d_in[1];
    const float* ea    = (const float*)d_in[2];
    const float* W1    = (const float*)d_in[3];
    const float* b1    = (const float*)d_in[4];
    const float* gamma = (const float*)d_in[5];
    const float* beta  = (const float*)d_in[6];
    const float* W2    = (const float*)d_in[7];
    const float* b2    = (const float*)d_in[8];
    float* out = (float*)d_out;

    int N = in_sizes[0] / D;
    int E = in_sizes[1] / 2;

    char* ws = (char*)d_ws;
    float* aggr = (float*)ws;                               // N*D floats
    size_t aggrBytes = (size_t)N * D * sizeof(float);
    float* gsum = (float*)(ws + aggrBytes);                 // D
    float* gsq  = gsum + D;                                 // D
    float* W2p  = gsq + D;                                  // D*D (16B-aligned)
    float* b2p  = W2p + D * D;                              // D

    // zero aggr + stats
    hipMemsetAsync(aggr, 0, aggrBytes + 1024, stream);

    int eBlocks = (int)(((long long)E * 32 + 255) / 256);
    k_edge<<<eBlocks, 256, 0, stream>>>(x, ei, ea, aggr, E);

    k_gemm1<<<2048, 256, 0, stream>>>(x, aggr, W1, b1, out, gsum, gsq, N);
    k_fold<<<1, 128, 0, stream>>>(gsum, gsq, gamma, beta, W2, b2, W2p, b2p, N);
    k_gemm2<<<2048, 256, 0, stream>>>(out, W2p, b2p, out, N);
}

// Round 3
// 995.477 us; speedup vs baseline: 3.2664x; 3.2664x over previous
//
#include <hip/hip_runtime.h>

#define D 128
#define BN_EPS 1e-5f
#define SB 256   // scan blocks
#define ST 256   // scan threads

// ---------------- 1. histogram: deg[dst]++ --------------------------------
__global__ __launch_bounds__(256) void k_hist(
    const int* __restrict__ ei, int* __restrict__ deg, int E)
{
    int e = blockIdx.x * 256 + threadIdx.x;
    if (e >= E) return;
    atomicAdd(&deg[ei[E + e]], 1);
}

// ---------------- 2a. per-block partial sums -------------------------------
__global__ __launch_bounds__(ST) void k_scanA(
    const int* __restrict__ deg, int* __restrict__ bsum, int N, int chunk)
{
    int b = blockIdx.x;
    int start = b * chunk, end = min(start + chunk, N);
    int s = 0;
    for (int i = start + threadIdx.x; i < end; i += ST) s += deg[i];
    __shared__ int red[ST];
    red[threadIdx.x] = s;
    __syncthreads();
    for (int o = ST / 2; o > 0; o >>= 1) {
        if (threadIdx.x < o) red[threadIdx.x] += red[threadIdx.x + o];
        __syncthreads();
    }
    if (threadIdx.x == 0) bsum[b] = red[0];
}

// ---------------- 2b. exclusive scan of block sums (1 block) ---------------
__global__ __launch_bounds__(SB) void k_scanB(int* __restrict__ bsum)
{
    __shared__ int tmp[SB];
    int t = threadIdx.x;
    int orig = bsum[t];
    tmp[t] = orig;
    __syncthreads();
    for (int o = 1; o < SB; o <<= 1) {
        int u = (t >= o) ? tmp[t - o] : 0;
        __syncthreads();
        tmp[t] += u;
        __syncthreads();
    }
    bsum[t] = tmp[t] - orig;   // exclusive
}

// ---------------- 2c. per-block scan with base → offsets + cursor ----------
__global__ __launch_bounds__(ST) void k_scanC(
    const int* __restrict__ deg, const int* __restrict__ bsum,
    int* __restrict__ offs, int* __restrict__ cur, int N, int chunk)
{
    int b = blockIdx.x;
    int start = b * chunk, end = min(start + chunk, N);
    __shared__ int tmp[ST];
    __shared__ int carry;
    int t = threadIdx.x;
    if (t == 0) carry = bsum[b];
    __syncthreads();
    for (int i0 = start; i0 < end; i0 += ST) {
        int i = i0 + t;
        int v = (i < end) ? deg[i] : 0;
        tmp[t] = v;
        __syncthreads();
        for (int o = 1; o < ST; o <<= 1) {
            int u = (t >= o) ? tmp[t - o] : 0;
            __syncthreads();
            tmp[t] += u;
            __syncthreads();
        }
        int incl = tmp[t];
        int total = tmp[ST - 1];
        if (i < end) {
            int ex = carry + incl - v;
            offs[i] = ex;
            cur[i] = ex;
        }
        __syncthreads();
        if (t == 0) carry += total;
        __syncthreads();
    }
}

// ---------------- 3. scatter (src, eid) into dst buckets -------------------
__global__ __launch_bounds__(256) void k_scatter(
    const int* __restrict__ ei, int* __restrict__ cur,
    int2* __restrict__ bucket, int E)
{
    int e = blockIdx.x * 256 + threadIdx.x;
    if (e >= E) return;
    int dst = ei[E + e];
    int pos = atomicAdd(&cur[dst], 1);
    bucket[pos] = make_int2(ei[e], e);
}

// ---------------- 4. aggregate: h[n] = x[n] + sum relu(x[src]+ea[eid]) -----
// one 64-lane wave per node, float2 per lane; h -> d_out
__global__ __launch_bounds__(256) void k_aggr(
    const float* __restrict__ x, const float* __restrict__ ea,
    const int2* __restrict__ bucket, const int* __restrict__ offs,
    const int* __restrict__ deg, float* __restrict__ h, int N)
{
    int node = blockIdx.x * 4 + (threadIdx.x >> 6);
    if (node >= N) return;
    int lane = threadIdx.x & 63;
    int c0 = 2 * lane;
    int start = offs[node];
    int d = deg[node];
    float2 acc = make_float2(0.f, 0.f);
    int2 nx = (d > 0) ? bucket[start] : make_int2(0, 0);
    for (int e = 0; e < d; ++e) {
        int2 se = nx;
        if (e + 1 < d) nx = bucket[start + e + 1];
        float2 xv = *(const float2*)(x + (size_t)se.x * D + c0);
        float2 ev = *(const float2*)(ea + (size_t)se.y * D + c0);
        acc.x += fmaxf(xv.x + ev.x, 0.f);
        acc.y += fmaxf(xv.y + ev.y, 0.f);
    }
    float2 xd = *(const float2*)(x + (size_t)node * D + c0);
    acc.x += xd.x;
    acc.y += xd.y;
    *(float2*)(h + (size_t)node * D + c0) = acc;
}

// ---------------- GEMM1 (round-1-proven pattern, in-place on d_out):
// h1 = relu(h @ W1 + b1); accumulate BN stats -------------------------------
__global__ __launch_bounds__(256) void k_gemm1(
    const float* __restrict__ hin, const float* __restrict__ W1,
    const float* __restrict__ b1, float* __restrict__ h1,
    float* __restrict__ gsum, float* __restrict__ gsq, int N)
{
    __shared__ float wS[D * D];
    __shared__ float rS[4][D];
    int tid = threadIdx.x;
    for (int i = tid * 4; i < D * D; i += 256 * 4)
        *(float4*)&wS[i] = *(const float4*)&W1[i];
    __syncthreads();

    int wv = tid >> 6, lane = tid & 63;
    int c0 = 2 * lane;
    float bb0 = b1[c0], bb1 = b1[c0 + 1];
    float s0 = 0.f, s1 = 0.f, q0 = 0.f, q1 = 0.f;

    for (int row = blockIdx.x * 4 + wv; row < N; row += gridDim.x * 4) {
        size_t base = (size_t)row * D;
        float2 hv = *(const float2*)&hin[base + c0];
        rS[wv][c0] = hv.x;
        rS[wv][c0 + 1] = hv.y;
        // wave-synchronous LDS (same wave wrote rS[wv]); DS ops are in-order
        float a0 = bb0, a1 = bb1;
        #pragma unroll
        for (int k = 0; k < D; k += 4) {
            float4 a = *(const float4*)&rS[wv][k];
            float2 w;
            w = *(const float2*)&wS[(k + 0) * D + c0]; a0 = fmaf(a.x, w.x, a0); a1 = fmaf(a.x, w.y, a1);
            w = *(const float2*)&wS[(k + 1) * D + c0]; a0 = fmaf(a.y, w.x, a0); a1 = fmaf(a.y, w.y, a1);
            w = *(const float2*)&wS[(k + 2) * D + c0]; a0 = fmaf(a.z, w.x, a0); a1 = fmaf(a.z, w.y, a1);
            w = *(const float2*)&wS[(k + 3) * D + c0]; a0 = fmaf(a.w, w.x, a0); a1 = fmaf(a.w, w.y, a1);
        }
        a0 = fmaxf(a0, 0.f);
        a1 = fmaxf(a1, 0.f);
        *(float2*)&h1[base + c0] = make_float2(a0, a1);
        s0 += a0; s1 += a1; q0 += a0 * a0; q1 += a1 * a1;
    }
    atomicAdd(&gsum[c0], s0);
    atomicAdd(&gsum[c0 + 1], s1);
    atomicAdd(&gsq[c0], q0);
    atomicAdd(&gsq[c0 + 1], q1);
}

// ---------------- fold BN into W2/b2 ---------------------------------------
__global__ __launch_bounds__(128) void k_fold(
    const float* __restrict__ gsum, const float* __restrict__ gsq,
    const float* __restrict__ gamma, const float* __restrict__ beta,
    const float* __restrict__ W2, const float* __restrict__ b2,
    float* __restrict__ W2p, float* __restrict__ b2p, int N)
{
    __shared__ float sS[D], tS[D];
    int j = threadIdx.x;
    float invN = 1.0f / (float)N;
    float mean = gsum[j] * invN;
    float var = gsq[j] * invN - mean * mean;
    float rstd = rsqrtf(var + BN_EPS);
    float s = rstd * gamma[j];
    sS[j] = s;
    tS[j] = beta[j] - mean * s;
    __syncthreads();
    float acc = b2[j];
    #pragma unroll 4
    for (int k = 0; k < D; ++k) {
        float w = W2[k * D + j];
        W2p[k * D + j] = sS[k] * w;
        acc = fmaf(tS[k], w, acc);
    }
    b2p[j] = acc;
}

// ---------------- GEMM2 (round-1-proven, in-place): out = h1 @ W2' + b2' ---
__global__ __launch_bounds__(256) void k_gemm2(
    const float* __restrict__ hin, const float* __restrict__ W2p,
    const float* __restrict__ b2p, float* __restrict__ out, int N)
{
    __shared__ float wS[D * D];
    __shared__ float rS[4][D];
    int tid = threadIdx.x;
    for (int i = tid * 4; i < D * D; i += 256 * 4)
        *(float4*)&wS[i] = *(const float4*)&W2p[i];
    __syncthreads();

    int wv = tid >> 6, lane = tid & 63;
    int c0 = 2 * lane;
    float bb0 = b2p[c0], bb1 = b2p[c0 + 1];

    for (int row = blockIdx.x * 4 + wv; row < N; row += gridDim.x * 4) {
        size_t base = (size_t)row * D;
        float2 hv = *(const float2*)&hin[base + c0];
        rS[wv][c0] = hv.x;
        rS[wv][c0 + 1] = hv.y;
        float a0 = bb0, a1 = bb1;
        #pragma unroll
        for (int k = 0; k < D; k += 4) {
            float4 a = *(const float4*)&rS[wv][k];
            float2 w;
            w = *(const float2*)&wS[(k + 0) * D + c0]; a0 = fmaf(a.x, w.x, a0); a1 = fmaf(a.x, w.y, a1);
            w = *(const float2*)&wS[(k + 1) * D + c0]; a0 = fmaf(a.y, w.x, a0); a1 = fmaf(a.y, w.y, a1);
            w = *(const float2*)&wS[(k + 2) * D + c0]; a0 = fmaf(a.z, w.x, a0); a1 = fmaf(a.z, w.y, a1);
            w = *(const float2*)&wS[(k + 3) * D + c0]; a0 = fmaf(a.w, w.x, a0); a1 = fmaf(a.w, w.y, a1);
        }
        *(float2*)&out[base + c0] = make_float2(a0, a1);
    }
}

extern "C" void kernel_launch(void* const* d_in, const int* in_sizes, int n_in,
                              void* d_out, int out_size, void* d_ws, size_t ws_size,
                              hipStream_t stream) {
    const float* x     = (const float*)d_in[0];
    const int*   ei    = (const int*)d_in[1];
    const float* ea    = (const float*)d_in[2];
    const float* W1    = (const float*)d_in[3];
    const float* b1    = (const float*)d_in[4];
    const float* gamma = (const float*)d_in[5];
    const float* beta  = (const float*)d_in[6];
    const float* W2    = (const float*)d_in[7];
    const float* b2    = (const float*)d_in[8];
    float* out = (float*)d_out;

    int N = in_sizes[0] / D;
    int E = in_sizes[1] / 2;

    // ---- workspace layout (total ~14.1 MB; round 1 proved >=51 MB is safe) ----
    char* ws = (char*)d_ws;
    int2*  bucket = (int2*)ws;                         // E int2 (12.8 MB)
    int*   deg    = (int*)(ws + (size_t)E * sizeof(int2)); // N
    int*   offs   = deg + N;                           // N
    int*   cur    = offs + N;                          // N
    int*   bsum   = cur + N;                           // SB
    float* gsum   = (float*)(bsum + SB);               // D
    float* gsq    = gsum + D;                          // D
    float* W2p    = gsq + D;                           // D*D
    float* b2p    = W2p + D * D;                       // D

    // zero deg + bsum + gsum + gsq (bucket/offs/cur fully overwritten)
    hipMemsetAsync(deg, 0, ((size_t)3 * N + SB) * sizeof(int) + 2 * D * sizeof(float), stream);

    int chunk = (N + SB - 1) / SB;
    int eB = (E + 255) / 256;

    k_hist<<<eB, 256, 0, stream>>>(ei, deg, E);
    k_scanA<<<SB, ST, 0, stream>>>(deg, bsum, N, chunk);
    k_scanB<<<1, SB, 0, stream>>>(bsum);
    k_scanC<<<SB, ST, 0, stream>>>(deg, bsum, offs, cur, N, chunk);
    k_scatter<<<eB, 256, 0, stream>>>(ei, cur, bucket, E);
    k_aggr<<<(N + 3) / 4, 256, 0, stream>>>(x, ea, bucket, offs, deg, out, N);

    k_gemm1<<<2048, 256, 0, stream>>>(out, W1, b1, out, gsum, gsq, N);
    k_fold<<<1, 128, 0, stream>>>(gsum, gsq, gamma, beta, W2, b2, W2p, b2p, N);
    k_gemm2<<<2048, 256, 0, stream>>>(out, W2p, b2p, out, N);
}

// Round 5
// 980.253 us; speedup vs baseline: 3.3171x; 1.0155x over previous
//
#include <hip/hip_runtime.h>

#define D 128
#define BN_EPS 1e-5f
#define SB 256   // scan blocks
#define ST 256   // scan threads

// ---------------- 1. histogram: deg[dst]++ --------------------------------
__global__ __launch_bounds__(256) void k_hist(
    const int* __restrict__ ei, int* __restrict__ deg, int E)
{
    int e = blockIdx.x * 256 + threadIdx.x;
    if (e >= E) return;
    atomicAdd(&deg[ei[E + e]], 1);
}

// ---------------- 2a. per-block partial sums -------------------------------
__global__ __launch_bounds__(ST) void k_scanA(
    const int* __restrict__ deg, int* __restrict__ bsum, int N, int chunk)
{
    int b = blockIdx.x;
    int start = b * chunk, end = min(start + chunk, N);
    int s = 0;
    for (int i = start + threadIdx.x; i < end; i += ST) s += deg[i];
    __shared__ int red[ST];
    red[threadIdx.x] = s;
    __syncthreads();
    for (int o = ST / 2; o > 0; o >>= 1) {
        if (threadIdx.x < o) red[threadIdx.x] += red[threadIdx.x + o];
        __syncthreads();
    }
    if (threadIdx.x == 0) bsum[b] = red[0];
}

// ---------------- 2b. exclusive scan of block sums (1 block) ---------------
__global__ __launch_bounds__(SB) void k_scanB(int* __restrict__ bsum)
{
    __shared__ int tmp[SB];
    int t = threadIdx.x;
    int orig = bsum[t];
    tmp[t] = orig;
    __syncthreads();
    for (int o = 1; o < SB; o <<= 1) {
        int u = (t >= o) ? tmp[t - o] : 0;
        __syncthreads();
        tmp[t] += u;
        __syncthreads();
    }
    bsum[t] = tmp[t] - orig;   // exclusive
}

// ---------------- 2c. per-block scan with base → offsets + cursor ----------
__global__ __launch_bounds__(ST) void k_scanC(
    const int* __restrict__ deg, const int* __restrict__ bsum,
    int* __restrict__ offs, int* __restrict__ cur, int N, int chunk)
{
    int b = blockIdx.x;
    int start = b * chunk, end = min(start + chunk, N);
    __shared__ int tmp[ST];
    __shared__ int carry;
    int t = threadIdx.x;
    if (t == 0) carry = bsum[b];
    __syncthreads();
    for (int i0 = start; i0 < end; i0 += ST) {
        int i = i0 + t;
        int v = (i < end) ? deg[i] : 0;
        tmp[t] = v;
        __syncthreads();
        for (int o = 1; o < ST; o <<= 1) {
            int u = (t >= o) ? tmp[t - o] : 0;
            __syncthreads();
            tmp[t] += u;
            __syncthreads();
        }
        int incl = tmp[t];
        int total = tmp[ST - 1];
        if (i < end) {
            int ex = carry + incl - v;
            offs[i] = ex;
            cur[i] = ex;
        }
        __syncthreads();
        if (t == 0) carry += total;
        __syncthreads();
    }
}

// ---------------- 3. scatter (src, eid) into dst buckets -------------------
__global__ __launch_bounds__(256) void k_scatter(
    const int* __restrict__ ei, int* __restrict__ cur,
    int2* __restrict__ bucket, int E)
{
    int e = blockIdx.x * 256 + threadIdx.x;
    if (e >= E) return;
    int dst = ei[E + e];
    int pos = atomicAdd(&cur[dst], 1);
    bucket[pos] = make_int2(ei[e], e);
}

// ---------------- 4. aggregate: h[n] = x[n] + sum relu(x[src]+ea[eid]) -----
// one 64-lane wave per node, float2 per lane; unroll x4: 8 independent
// row-loads in flight per lane; h -> d_out
__global__ __launch_bounds__(256) void k_aggr(
    const float* __restrict__ x, const float* __restrict__ ea,
    const int2* __restrict__ bucket, const int* __restrict__ offs,
    const int* __restrict__ deg, float* __restrict__ h, int N)
{
    int node = blockIdx.x * 4 + (threadIdx.x >> 6);
    if (node >= N) return;
    int lane = threadIdx.x & 63;
    int c0 = 2 * lane;
    int start = offs[node];
    int d = deg[node];
    const int2* bp = bucket + start;

    float2 acc = *(const float2*)(x + (size_t)node * D + c0);  // (1+eps)*x_i, eps=0

    int e = 0;
    for (; e + 4 <= d; e += 4) {
        int2 b0 = bp[e];
        int2 b1 = bp[e + 1];
        int2 b2 = bp[e + 2];
        int2 b3 = bp[e + 3];
        float2 x0 = *(const float2*)(x + (size_t)b0.x * D + c0);
        float2 a0 = *(const float2*)(ea + (size_t)b0.y * D + c0);
        float2 x1 = *(const float2*)(x + (size_t)b1.x * D + c0);
        float2 a1 = *(const float2*)(ea + (size_t)b1.y * D + c0);
        float2 x2 = *(const float2*)(x + (size_t)b2.x * D + c0);
        float2 a2 = *(const float2*)(ea + (size_t)b2.y * D + c0);
        float2 x3 = *(const float2*)(x + (size_t)b3.x * D + c0);
        float2 a3 = *(const float2*)(ea + (size_t)b3.y * D + c0);
        acc.x += fmaxf(x0.x + a0.x, 0.f) + fmaxf(x1.x + a1.x, 0.f)
               + fmaxf(x2.x + a2.x, 0.f) + fmaxf(x3.x + a3.x, 0.f);
        acc.y += fmaxf(x0.y + a0.y, 0.f) + fmaxf(x1.y + a1.y, 0.f)
               + fmaxf(x2.y + a2.y, 0.f) + fmaxf(x3.y + a3.y, 0.f);
    }
    for (; e < d; ++e) {
        int2 b = bp[e];
        float2 xv = *(const float2*)(x + (size_t)b.x * D + c0);
        float2 av = *(const float2*)(ea + (size_t)b.y * D + c0);
        acc.x += fmaxf(xv.x + av.x, 0.f);
        acc.y += fmaxf(xv.y + av.y, 0.f);
    }
    *(float2*)(h + (size_t)node * D + c0) = acc;
}

// ---------------- GEMM1 (round-3-proven pattern, in-place on d_out):
// h1 = relu(h @ W1 + b1); accumulate BN stats -------------------------------
__global__ __launch_bounds__(256) void k_gemm1(
    const float* __restrict__ hin, const float* __restrict__ W1,
    const float* __restrict__ b1, float* __restrict__ h1,
    float* __restrict__ gsum, float* __restrict__ gsq, int N)
{
    __shared__ float wS[D * D];
    __shared__ float rS[4][D];
    int tid = threadIdx.x;
    for (int i = tid * 4; i < D * D; i += 256 * 4)
        *(float4*)&wS[i] = *(const float4*)&W1[i];
    __syncthreads();

    int wv = tid >> 6, lane = tid & 63;
    int c0 = 2 * lane;
    float bb0 = b1[c0], bb1 = b1[c0 + 1];
    float s0 = 0.f, s1 = 0.f, q0 = 0.f, q1 = 0.f;

    for (int row = blockIdx.x * 4 + wv; row < N; row += gridDim.x * 4) {
        size_t base = (size_t)row * D;
        float2 hv = *(const float2*)&hin[base + c0];
        rS[wv][c0] = hv.x;
        rS[wv][c0 + 1] = hv.y;
        // wave-synchronous LDS (same wave wrote rS[wv]); DS ops are in-order
        float a0 = bb0, a1 = bb1;
        #pragma unroll
        for (int k = 0; k < D; k += 4) {
            float4 a = *(const float4*)&rS[wv][k];
            float2 w;
            w = *(const float2*)&wS[(k + 0) * D + c0]; a0 = fmaf(a.x, w.x, a0); a1 = fmaf(a.x, w.y, a1);
            w = *(const float2*)&wS[(k + 1) * D + c0]; a0 = fmaf(a.y, w.x, a0); a1 = fmaf(a.y, w.y, a1);
            w = *(const float2*)&wS[(k + 2) * D + c0]; a0 = fmaf(a.z, w.x, a0); a1 = fmaf(a.z, w.y, a1);
            w = *(const float2*)&wS[(k + 3) * D + c0]; a0 = fmaf(a.w, w.x, a0); a1 = fmaf(a.w, w.y, a1);
        }
        a0 = fmaxf(a0, 0.f);
        a1 = fmaxf(a1, 0.f);
        *(float2*)&h1[base + c0] = make_float2(a0, a1);
        s0 += a0; s1 += a1; q0 += a0 * a0; q1 += a1 * a1;
    }
    atomicAdd(&gsum[c0], s0);
    atomicAdd(&gsum[c0 + 1], s1);
    atomicAdd(&gsq[c0], q0);
    atomicAdd(&gsq[c0 + 1], q1);
}

// ---------------- fold BN into W2/b2 ---------------------------------------
__global__ __launch_bounds__(128) void k_fold(
    const float* __restrict__ gsum, const float* __restrict__ gsq,
    const float* __restrict__ gamma, const float* __restrict__ beta,
    const float* __restrict__ W2, const float* __restrict__ b2,
    float* __restrict__ W2p, float* __restrict__ b2p, int N)
{
    __shared__ float sS[D], tS[D];
    int j = threadIdx.x;
    float invN = 1.0f / (float)N;
    float mean = gsum[j] * invN;
    float var = gsq[j] * invN - mean * mean;
    float rstd = rsqrtf(var + BN_EPS);
    float s = rstd * gamma[j];
    sS[j] = s;
    tS[j] = beta[j] - mean * s;
    __syncthreads();
    float acc = b2[j];
    #pragma unroll 4
    for (int k = 0; k < D; ++k) {
        float w = W2[k * D + j];
        W2p[k * D + j] = sS[k] * w;
        acc = fmaf(tS[k], w, acc);
    }
    b2p[j] = acc;
}

// ---------------- GEMM2 (round-3-proven, in-place): out = h1 @ W2' + b2' ---
__global__ __launch_bounds__(256) void k_gemm2(
    const float* __restrict__ hin, const float* __restrict__ W2p,
    const float* __restrict__ b2p, float* __restrict__ out, int N)
{
    __shared__ float wS[D * D];
    __shared__ float rS[4][D];
    int tid = threadIdx.x;
    for (int i = tid * 4; i < D * D; i += 256 * 4)
        *(float4*)&wS[i] = *(const float4*)&W2p[i];
    __syncthreads();

    int wv = tid >> 6, lane = tid & 63;
    int c0 = 2 * lane;
    float bb0 = b2p[c0], bb1 = b2p[c0 + 1];

    for (int row = blockIdx.x * 4 + wv; row < N; row += gridDim.x * 4) {
        size_t base = (size_t)row * D;
        float2 hv = *(const float2*)&hin[base + c0];
        rS[wv][c0] = hv.x;
        rS[wv][c0 + 1] = hv.y;
        float a0 = bb0, a1 = bb1;
        #pragma unroll
        for (int k = 0; k < D; k += 4) {
            float4 a = *(const float4*)&rS[wv][k];
            float2 w;
            w = *(const float2*)&wS[(k + 0) * D + c0]; a0 = fmaf(a.x, w.x, a0); a1 = fmaf(a.x, w.y, a1);
            w = *(const float2*)&wS[(k + 1) * D + c0]; a0 = fmaf(a.y, w.x, a0); a1 = fmaf(a.y, w.y, a1);
            w = *(const float2*)&wS[(k + 2) * D + c0]; a0 = fmaf(a.z, w.x, a0); a1 = fmaf(a.z, w.y, a1);
            w = *(const float2*)&wS[(k + 3) * D + c0]; a0 = fmaf(a.w, w.x, a0); a1 = fmaf(a.w, w.y, a1);
        }
        *(float2*)&out[base + c0] = make_float2(a0, a1);
    }
}

extern "C" void kernel_launch(void* const* d_in, const int* in_sizes, int n_in,
                              void* d_out, int out_size, void* d_ws, size_t ws_size,
                              hipStream_t stream) {
    const float* x     = (const float*)d_in[0];
    const int*   ei    = (const int*)d_in[1];
    const float* ea    = (const float*)d_in[2];
    const float* W1    = (const float*)d_in[3];
    const float* b1    = (const float*)d_in[4];
    const float* gamma = (const float*)d_in[5];
    const float* beta  = (const float*)d_in[6];
    const float* W2    = (const float*)d_in[7];
    const float* b2    = (const float*)d_in[8];
    float* out = (float*)d_out;

    int N = in_sizes[0] / D;
    int E = in_sizes[1] / 2;

    // ---- workspace layout (~14.1 MB, proven safe; ws_size is ~3.3 GB) ----
    char* ws = (char*)d_ws;
    int2*  bucket = (int2*)ws;                             // E int2 (12.8 MB)
    int*   deg    = (int*)(ws + (size_t)E * sizeof(int2)); // N
    int*   offs   = deg + N;                               // N
    int*   cur    = offs + N;                              // N
    int*   bsum   = cur + N;                               // SB
    float* gsum   = (float*)(bsum + SB);                   // D
    float* gsq    = gsum + D;                              // D
    float* W2p    = gsq + D;                               // D*D
    float* b2p    = W2p + D * D;                           // D

    // zero deg + bsum + gsum + gsq (bucket/offs/cur fully overwritten)
    hipMemsetAsync(deg, 0, ((size_t)3 * N + SB) * sizeof(int) + 2 * D * sizeof(float), stream);

    int chunk = (N + SB - 1) / SB;
    int eB = (E + 255) / 256;

    k_hist<<<eB, 256, 0, stream>>>(ei, deg, E);
    k_scanA<<<SB, ST, 0, stream>>>(deg, bsum, N, chunk);
    k_scanB<<<1, SB, 0, stream>>>(bsum);
    k_scanC<<<SB, ST, 0, stream>>>(deg, bsum, offs, cur, N, chunk);
    k_scatter<<<eB, 256, 0, stream>>>(ei, cur, bucket, E);
    k_aggr<<<(N + 3) / 4, 256, 0, stream>>>(x, ea, bucket, offs, deg, out, N);

    k_gemm1<<<2048, 256, 0, stream>>>(out, W1, b1, out, gsum, gsq, N);
    k_fold<<<1, 128, 0, stream>>>(gsum, gsq, gamma, beta, W2, b2, W2p, b2p, N);
    k_gemm2<<<2048, 256, 0, stream>>>(out, W2p, b2p, out, N);
}